// Round 6
// baseline (642.290 us; speedup 1.0000x reference)
//
#include <hip/hip_runtime.h>
#include <hip/hip_cooperative_groups.h>
#include <hip/hip_bf16.h>
#include <hip/hip_fp16.h>

// DFAChebNet forward.
//  layer: x@W0 + (agg(x)-x)@W1 + b == x@(W0-W1) + agg(x@W1) + b   (project first)
//  R17: ONE cooperative dispatch. R16 put every kernel under 40us; the
//  remaining ~50-75us of the 213.8us wall is 7-dispatch launch/drain
//  overhead. All phases merged into k_mega with 6 grid.sync()s:
//    P0 zero cursors | P1 partition (direct scatter, no 40KB LDS stage)
//    P2 bucket sort  | P3 proj1 (MFMA) | P4 gather1 | P5 gather2 | P6 lsm
//  Phase math is R16-verbatim. Gathers: dual-node interleave (R15), now
//  grid-stride persistent w/ next-pair descriptor prefetch. bfrag builds
//  hoisted out of persistent tile loops. Grid = co-resident capacity via
//  occupancy query (cached host-side, capture-safe).

namespace cg = cooperative_groups;

constexpr int NN   = 100000;
constexpr int NE   = 1600000;
constexpr int FIN  = 128;
constexpr int HID  = 16;
constexpr int NCLS = 32;

constexpr int RB    = 256;                         // rows per bucket
constexpr int NBKT  = (NN + RB - 1) / RB;          // 391
constexpr int EPB   = 4096;                        // edges per partition block
constexpr int EPT   = EPB / 256;                   // 16 edges per thread
constexpr int GP    = (NE + EPB - 1) / EPB;        // 391
constexpr int CAP   = 8192;                        // bucket slot capacity (mean 4096)
constexpr int NTILE = NN / 16;                     // 6250 MFMA tiles (exact)
constexpr int NPAIR = NN / 2;                      // 50000 dual-node pairs

typedef float f32x2 __attribute__((ext_vector_type(2)));
typedef float f32x4 __attribute__((ext_vector_type(4)));
typedef short bf16x8 __attribute__((ext_vector_type(8)));

#if defined(__has_builtin)
#if __has_builtin(__builtin_amdgcn_cvt_pk_f32_fp8)
#define HAVE_CVT_FP8 1
#endif
#endif

// fp8 e4m3fn encode (RNE, subnormals flushed to 0, clamp at 448)
static __device__ __forceinline__ unsigned int f2e4m3(float f) {
    union { float f; unsigned int u; } v; v.f = f;
    unsigned int s = (v.u >> 24) & 0x80u;
    unsigned int au = v.u & 0x7fffffffu;
    if (au > 0x43E00000u) au = 0x43E00000u;        // clamp to 448
    au += 0x7ffffu + ((au >> 20) & 1u);            // RNE into 3-bit mantissa
    int e4 = (int)(au >> 23) - 120;                // 127-7
    unsigned int m = (au >> 20) & 7u;
    unsigned int byte = (e4 <= 0) ? 0u : (((unsigned int)e4 << 3) | m);
    return s | byte;
}
// 4 packed fp8 -> acc[0..3] += w * val
static __device__ __forceinline__ void fp8x4_fma(unsigned int v, float w, float* acc) {
#ifdef HAVE_CVT_FP8
    f32x2 lo = __builtin_amdgcn_cvt_pk_f32_fp8((int)v, false);
    f32x2 hi = __builtin_amdgcn_cvt_pk_f32_fp8((int)v, true);
    acc[0] += w * lo.x; acc[1] += w * lo.y;
    acc[2] += w * hi.x; acc[3] += w * hi.y;
#else
#pragma unroll
    for (int i = 0; i < 4; i++) {
        unsigned int b = (v >> (8 * i)) & 0xffu;
        float f = __int_as_float((int)(((b & 0x80u) << 24) | ((b & 0x7fu) << 20))) * 0x1p120f;
        acc[i] += w * f;
    }
#endif
}
// bf16 RNE
static __device__ __forceinline__ unsigned short f2bf(float f) {
    union { float f; unsigned int u; } v; v.f = f;
    unsigned int r = v.u + 0x7fffu + ((v.u >> 16) & 1u);
    return (unsigned short)(r >> 16);
}
// edge record: col(17 bits) | w(15 bits = signless bf16, RNE)
static __device__ __forceinline__ unsigned int wpack(float wf) {
    unsigned int b = __float_as_uint(wf) + 0x8000u;
    return (b >> 16) & 0x7fffu;
}
static __device__ __forceinline__ float wdec(unsigned int u) {
    return __uint_as_float((u >> 17) << 16);
}

__global__ __launch_bounds__(256, 4) void k_mega(
    const float* __restrict__ x, const int* __restrict__ row,
    const int* __restrict__ col, const float* __restrict__ ew,
    const float* __restrict__ W1_0, const float* __restrict__ W1_1,
    const float* __restrict__ b1,
    const float* __restrict__ W2_0, const float* __restrict__ W2_1,
    const float* __restrict__ b2, float* __restrict__ out,
    int2* __restrict__ partS, unsigned int* __restrict__ partC,
    int* __restrict__ bucketCursor, int* __restrict__ rowptr,
    float* __restrict__ dinv, float* __restrict__ xa,
    unsigned short* __restrict__ h16, unsigned short* __restrict__ g16,
    unsigned char* __restrict__ xb8, unsigned char* __restrict__ h8) {
    cg::grid_group grid = cg::this_grid();
    int bid = blockIdx.x, tid = threadIdx.x;
    int lane = tid & 63;
    int TW = (int)(gridDim.x << 2);              // total waves
    int gw = (bid << 2) | (tid >> 6);            // global wave id

    __shared__ int sh_cnt[NBKT];
    __shared__ int sh_gbase[NBKT];
    __shared__ int sh_lcur[NBKT];
    __shared__ int sh_hist[RB];
    __shared__ int sh_cursor[RB];
    __shared__ float sh_dsum[RB];
    __shared__ int sh_wtot[4];
    __shared__ int sh_red[4];

    // ---- P0: zero bucket cursors ----
    for (int i = bid * 256 + tid; i < NBKT; i += (int)gridDim.x * 256)
        bucketCursor[i] = 0;
    grid.sync();

    // ---- P1: partition, direct scatter (no LDS stage). Per-(block,bucket)
    // records land contiguously in the reserved range -> ~2-line runs.
    if (bid < GP) {
        long ebase = (long)bid * EPB;
        int rr[EPT]; int cc[EPT]; float wv[EPT];
#pragma unroll
        for (int i = 0; i < EPT; i++) {
            long e = ebase + i * 256 + tid;
            if (e < NE) { rr[i] = row[e]; cc[i] = col[e]; wv[i] = ew[e]; }
            else rr[i] = -1;
        }
        for (int i = tid; i < NBKT; i += 256) { sh_cnt[i] = 0; sh_lcur[i] = 0; }
        __syncthreads();
#pragma unroll
        for (int i = 0; i < EPT; i++)
            if (rr[i] >= 0) atomicAdd(&sh_cnt[rr[i] >> 8], 1);
        __syncthreads();
        for (int i = tid; i < NBKT; i += 256) {
            int c = sh_cnt[i];
            sh_gbase[i] = i * CAP + ((c > 0) ? atomicAdd(&bucketCursor[i], c) : 0);
        }
        __syncthreads();
#pragma unroll
        for (int i = 0; i < EPT; i++) {
            if (rr[i] >= 0) {
                int b = rr[i] >> 8;
                int pos = atomicAdd(&sh_lcur[b], 1);
                int2 v;
                v.x = cc[i] | ((rr[i] & 255) << 17);
                v.y = __float_as_int(wv[i]);
                partS[sh_gbase[b] + pos] = v;
            }
        }
    }
    grid.sync();

    // ---- P2: per-bucket sort by row; packed 4B CSR + rowptr + dinv ----
    if (bid < NBKT) {
        int b = bid;
        int wv = tid >> 6;
        // inline exclusive scan: start = sum_{i<b} count_i
        int partial = 0;
        for (int i = tid; i < b; i += 256) partial += bucketCursor[i];
#pragma unroll
        for (int off = 1; off < 64; off <<= 1) partial += __shfl_xor(partial, off, 64);
        if (lane == 0) sh_red[wv] = partial;
        sh_hist[tid] = 0;
        sh_dsum[tid] = 0.f;
        __syncthreads();
        int start = sh_red[0] + sh_red[1] + sh_red[2] + sh_red[3];
        int count = bucketCursor[b];
        const int2* src = partS + (long)b * CAP;
        for (int i = tid; i < count; i += 256)
            atomicAdd(&sh_hist[((unsigned)src[i].x >> 17) & 255], 1);
        __syncthreads();
        int v = sh_hist[tid];
        int sc = v;
#pragma unroll
        for (int off = 1; off < 64; off <<= 1) {
            int up = __shfl_up(sc, off, 64);
            if (lane >= off) sc += up;
        }
        if (lane == 63) sh_wtot[wv] = sc;
        __syncthreads();
        int add = 0;
        for (int w2 = 0; w2 < wv; w2++) add += sh_wtot[w2];
        int ex = sc + add - v;
        int node = b * RB + tid;
        if (node <= NN) rowptr[node] = start + ex;   // node==NN -> NE
        sh_cursor[tid] = ex;
        __syncthreads();
        for (int i = tid; i < count; i += 256) {
            int2 p = src[i];
            int rl = ((unsigned)p.x >> 17) & 255;
            int pos = atomicAdd(&sh_cursor[rl], 1);
            float wf = __int_as_float(p.y);
            partC[start + pos] = ((unsigned)p.x & 0x1FFFFu) | (wpack(wf) << 17);
            atomicAdd(&sh_dsum[rl], wf);
        }
        __syncthreads();
        if (node < NN) {
            float dsv = sh_dsum[tid];
            dinv[node] = dsv > 0.f ? rsqrtf(dsv) : 0.f;
        }
    }
    grid.sync();

    // ---- P3: proj1 (MFMA). xa = x@(W1_0-W1_1)+b1; xb8 = fp8(dinv*(x@W1_1)).
    {
        int pcol = lane & 15, quad = lane >> 4;
        // B fragments built once per wave (persistent loop follows)
        bf16x8 bfrag[2][4];
#pragma unroll
        for (int mat = 0; mat < 2; mat++) {
            const float* W = mat ? W1_1 : W1_0;
#pragma unroll
            for (int kb = 0; kb < 4; kb++) {
                bf16x8 f;
#pragma unroll
                for (int j = 0; j < 8; j++)
                    f[j] = (short)f2bf(W[(kb * 32 + quad * 8 + j) * HID + pcol]);
                bfrag[mat][kb] = f;
            }
        }
        float b1v = b1[pcol];
        for (int wid = gw; wid < NTILE; wid += TW) {
            const float* xrow = x + ((long)wid * 16 + pcol) * FIN + quad * 8;
            float4 xb[8];
#pragma unroll
            for (int kb = 0; kb < 4; kb++) {
                xb[2 * kb]     = *(const float4*)(xrow + kb * 32);
                xb[2 * kb + 1] = *(const float4*)(xrow + kb * 32 + 4);
            }
            f32x4 acc0 = {0.f, 0.f, 0.f, 0.f}, acc1 = {0.f, 0.f, 0.f, 0.f};
#pragma unroll
            for (int kb = 0; kb < 4; kb++) {
                float4 a0 = xb[2 * kb], a1 = xb[2 * kb + 1];
                bf16x8 af;
                af[0] = (short)f2bf(a0.x); af[1] = (short)f2bf(a0.y);
                af[2] = (short)f2bf(a0.z); af[3] = (short)f2bf(a0.w);
                af[4] = (short)f2bf(a1.x); af[5] = (short)f2bf(a1.y);
                af[6] = (short)f2bf(a1.z); af[7] = (short)f2bf(a1.w);
                acc0 = __builtin_amdgcn_mfma_f32_16x16x32_bf16(af, bfrag[0][kb], acc0, 0, 0, 0);
                acc1 = __builtin_amdgcn_mfma_f32_16x16x32_bf16(af, bfrag[1][kb], acc1, 0, 0, 0);
            }
#pragma unroll
            for (int r = 0; r < 4; r++) {
                long node = (long)wid * 16 + quad * 4 + r;
                float a0 = acc0[r], a1 = acc1[r];
                xa[node * HID + pcol] = a0 - a1 + b1v;
                float dn = dinv[node];
                xb8[node * HID + pcol] = (unsigned char)f2e4m3(dn * a1);
            }
        }
    }
    grid.sync();

    // ---- P4: gather1 (dual-node persistent). h16=bf16(relu(xa+dn*agg)),
    //          h8=fp8(dn*h). lane = (d 0..3, p 0..15).
    {
        int d = lane & 3, p = lane >> 2;
        int pr = gw;
        int s0 = 0, e0 = 0, e1 = 0; float2 dnv = {0.f, 0.f};
        if (pr < NPAIR) {
            s0 = rowptr[2 * pr]; e0 = rowptr[2 * pr + 1]; e1 = rowptr[2 * pr + 2];
            dnv = *(const float2*)(dinv + 2 * pr);
        }
        while (pr < NPAIR) {
            int np = pr + TW;
            int s0n = 0, e0n = 0, e1n = 0; float2 dnvn = {0.f, 0.f};
            if (np < NPAIR) {
                s0n = rowptr[2 * np]; e0n = rowptr[2 * np + 1]; e1n = rowptr[2 * np + 2];
                dnvn = *(const float2*)(dinv + 2 * np);
            }
            long n0 = (long)pr * 2, n1 = n0 + 1;
            float4 xav0 = *(const float4*)(xa + n0 * HID + d * 4);
            float4 xav1 = *(const float4*)(xa + n1 * HID + d * 4);
            float acc0[4] = {0.f, 0.f, 0.f, 0.f};
            float acc1[4] = {0.f, 0.f, 0.f, 0.f};
            int j0 = s0 + p, j1 = e0 + p;
            while ((j0 < e0) | (j1 < e1)) {
                if (j0 < e0) {
                    unsigned int u = partC[j0];
                    unsigned int v = *(const unsigned int*)(xb8 + (u & 0x1FFFF) * HID + d * 4);
                    fp8x4_fma(v, wdec(u), acc0);
                    j0 += 16;
                }
                if (j1 < e1) {
                    unsigned int u = partC[j1];
                    unsigned int v = *(const unsigned int*)(xb8 + (u & 0x1FFFF) * HID + d * 4);
                    fp8x4_fma(v, wdec(u), acc1);
                    j1 += 16;
                }
            }
#pragma unroll
            for (int i = 0; i < 4; i++) {
                acc0[i] += __shfl_xor(acc0[i], 4);  acc1[i] += __shfl_xor(acc1[i], 4);
                acc0[i] += __shfl_xor(acc0[i], 8);  acc1[i] += __shfl_xor(acc1[i], 8);
                acc0[i] += __shfl_xor(acc0[i], 16); acc1[i] += __shfl_xor(acc1[i], 16);
                acc0[i] += __shfl_xor(acc0[i], 32); acc1[i] += __shfl_xor(acc1[i], 32);
            }
            if (p == 0) {   // lanes 0..3 (lane == d)
                float h0[4], h1[4];
                h0[0] = fmaxf(xav0.x + dnv.x * acc0[0], 0.f);
                h0[1] = fmaxf(xav0.y + dnv.x * acc0[1], 0.f);
                h0[2] = fmaxf(xav0.z + dnv.x * acc0[2], 0.f);
                h0[3] = fmaxf(xav0.w + dnv.x * acc0[3], 0.f);
                h1[0] = fmaxf(xav1.x + dnv.y * acc1[0], 0.f);
                h1[1] = fmaxf(xav1.y + dnv.y * acc1[1], 0.f);
                h1[2] = fmaxf(xav1.z + dnv.y * acc1[2], 0.f);
                h1[3] = fmaxf(xav1.w + dnv.y * acc1[3], 0.f);
                ushort4 u0, u1;
                u0.x = f2bf(h0[0]); u0.y = f2bf(h0[1]); u0.z = f2bf(h0[2]); u0.w = f2bf(h0[3]);
                u1.x = f2bf(h1[0]); u1.y = f2bf(h1[1]); u1.z = f2bf(h1[2]); u1.w = f2bf(h1[3]);
                *(ushort4*)(h16 + n0 * HID + d * 4) = u0;
                *(ushort4*)(h16 + n1 * HID + d * 4) = u1;
                unsigned int p0 = f2e4m3(dnv.x * h0[0]) | (f2e4m3(dnv.x * h0[1]) << 8)
                                | (f2e4m3(dnv.x * h0[2]) << 16) | (f2e4m3(dnv.x * h0[3]) << 24);
                unsigned int p1 = f2e4m3(dnv.y * h1[0]) | (f2e4m3(dnv.y * h1[1]) << 8)
                                | (f2e4m3(dnv.y * h1[2]) << 16) | (f2e4m3(dnv.y * h1[3]) << 24);
                *(unsigned int*)(h8 + n0 * HID + d * 4) = p0;
                *(unsigned int*)(h8 + n1 * HID + d * 4) = p1;
            }
            pr = np; s0 = s0n; e0 = e0n; e1 = e1n; dnv = dnvn;
        }
    }
    grid.sync();

    // ---- P5: gather2 (dual-node persistent). g16 = bf16(dn * agg(h8)). ----
    {
        int d = lane & 3, p = lane >> 2;
        int pr = gw;
        int s0 = 0, e0 = 0, e1 = 0; float2 dnv = {0.f, 0.f};
        if (pr < NPAIR) {
            s0 = rowptr[2 * pr]; e0 = rowptr[2 * pr + 1]; e1 = rowptr[2 * pr + 2];
            dnv = *(const float2*)(dinv + 2 * pr);
        }
        while (pr < NPAIR) {
            int np = pr + TW;
            int s0n = 0, e0n = 0, e1n = 0; float2 dnvn = {0.f, 0.f};
            if (np < NPAIR) {
                s0n = rowptr[2 * np]; e0n = rowptr[2 * np + 1]; e1n = rowptr[2 * np + 2];
                dnvn = *(const float2*)(dinv + 2 * np);
            }
            long n0 = (long)pr * 2, n1 = n0 + 1;
            float acc0[4] = {0.f, 0.f, 0.f, 0.f};
            float acc1[4] = {0.f, 0.f, 0.f, 0.f};
            int j0 = s0 + p, j1 = e0 + p;
            while ((j0 < e0) | (j1 < e1)) {
                if (j0 < e0) {
                    unsigned int u = partC[j0];
                    unsigned int v = *(const unsigned int*)(h8 + (u & 0x1FFFF) * HID + d * 4);
                    fp8x4_fma(v, wdec(u), acc0);
                    j0 += 16;
                }
                if (j1 < e1) {
                    unsigned int u = partC[j1];
                    unsigned int v = *(const unsigned int*)(h8 + (u & 0x1FFFF) * HID + d * 4);
                    fp8x4_fma(v, wdec(u), acc1);
                    j1 += 16;
                }
            }
#pragma unroll
            for (int i = 0; i < 4; i++) {
                acc0[i] += __shfl_xor(acc0[i], 4);  acc1[i] += __shfl_xor(acc1[i], 4);
                acc0[i] += __shfl_xor(acc0[i], 8);  acc1[i] += __shfl_xor(acc1[i], 8);
                acc0[i] += __shfl_xor(acc0[i], 16); acc1[i] += __shfl_xor(acc1[i], 16);
                acc0[i] += __shfl_xor(acc0[i], 32); acc1[i] += __shfl_xor(acc1[i], 32);
            }
            if (p == 0) {
                ushort4 u0, u1;
                u0.x = f2bf(dnv.x * acc0[0]); u0.y = f2bf(dnv.x * acc0[1]);
                u0.z = f2bf(dnv.x * acc0[2]); u0.w = f2bf(dnv.x * acc0[3]);
                u1.x = f2bf(dnv.y * acc1[0]); u1.y = f2bf(dnv.y * acc1[1]);
                u1.z = f2bf(dnv.y * acc1[2]); u1.w = f2bf(dnv.y * acc1[3]);
                *(ushort4*)(g16 + n0 * HID + d * 4) = u0;
                *(ushort4*)(g16 + n1 * HID + d * 4) = u1;
            }
            pr = np; s0 = s0n; e0 = e0n; e1 = e1n; dnv = dnvn;
        }
    }
    grid.sync();

    // ---- P6: lsm (MFMA). v = [h16;g16]@[W2_0-W2_1;W2_1] + b2; log-softmax.
    {
        int pcol = lane & 15, quad = lane >> 4;
        bf16x8 bfrag[2];
#pragma unroll
        for (int c = 0; c < 2; c++) {
            bf16x8 f;
            if (quad < 2) {
#pragma unroll
                for (int j = 0; j < 8; j++) {
                    int k = quad * 8 + j;
                    f[j] = (short)f2bf(W2_0[k * NCLS + pcol + 16 * c] - W2_1[k * NCLS + pcol + 16 * c]);
                }
            } else {
#pragma unroll
                for (int j = 0; j < 8; j++) {
                    int k = (quad - 2) * 8 + j;
                    f[j] = (short)f2bf(W2_1[k * NCLS + pcol + 16 * c]);
                }
            }
            bfrag[c] = f;
        }
        float b2a = b2[pcol], b2b = b2[pcol + 16];
        for (int wid = gw; wid < NTILE; wid += TW) {
            long node_a = (long)wid * 16 + pcol;
            const unsigned short* abase =
                (quad & 2) ? (g16 + node_a * HID + (quad & 1) * 8)
                           : (h16 + node_a * HID + (quad & 1) * 8);
            bf16x8 af = *(const bf16x8*)abase;
            f32x4 c0 = {0.f, 0.f, 0.f, 0.f}, c1 = {0.f, 0.f, 0.f, 0.f};
            c0 = __builtin_amdgcn_mfma_f32_16x16x32_bf16(af, bfrag[0], c0, 0, 0, 0);
            c1 = __builtin_amdgcn_mfma_f32_16x16x32_bf16(af, bfrag[1], c1, 0, 0, 0);
#pragma unroll
            for (int r = 0; r < 4; r++) {
                long node = (long)wid * 16 + quad * 4 + r;
                float v0 = c0[r] + b2a;
                float v1 = c1[r] + b2b;
                float m = fmaxf(v0, v1);
                m = fmaxf(m, __shfl_xor(m, 1));
                m = fmaxf(m, __shfl_xor(m, 2));
                m = fmaxf(m, __shfl_xor(m, 4));
                m = fmaxf(m, __shfl_xor(m, 8));
                float sum = __expf(v0 - m) + __expf(v1 - m);
                sum += __shfl_xor(sum, 1);
                sum += __shfl_xor(sum, 2);
                sum += __shfl_xor(sum, 4);
                sum += __shfl_xor(sum, 8);
                float ls = logf(sum);
                out[node * NCLS + pcol] = v0 - m - ls;
                out[node * NCLS + pcol + 16] = v1 - m - ls;
            }
        }
    }
}

extern "C" void kernel_launch(void* const* d_in, const int* in_sizes, int n_in,
                              void* d_out, int out_size, void* d_ws, size_t ws_size,
                              hipStream_t stream) {
    const float* x    = (const float*)d_in[0];
    const int*   ei   = (const int*)d_in[1];
    const float* ew   = (const float*)d_in[2];
    const float* W1_0 = (const float*)d_in[3];
    const float* W1_1 = (const float*)d_in[4];
    const float* b1   = (const float*)d_in[5];
    const float* W2_0 = (const float*)d_in[6];
    const float* W2_1 = (const float*)d_in[7];
    const float* b2   = (const float*)d_in[8];
    float* out = (float*)d_out;

    const int* row = ei;
    const int* col = ei + NE;

    char* ws = (char*)d_ws;
    int2*  partS     = (int2*)ws;                 ws += sizeof(int2) * (long)NBKT * CAP;
    unsigned int* partC = (unsigned int*)ws;      ws += sizeof(int) * NE;
    int*   bucketCursor = (int*)ws;               ws += sizeof(int) * NBKT;
    int*   rowptr    = (int*)ws;                  ws += sizeof(int) * (NN + 4);
    float* dinv      = (float*)ws;                ws += sizeof(float) * NN;
    float* xa        = (float*)ws;                ws += sizeof(float) * NN * HID;
    unsigned short* h16 = (unsigned short*)ws;    ws += sizeof(short) * NN * HID;
    unsigned short* g16 = (unsigned short*)ws;    ws += sizeof(short) * NN * HID;
    unsigned char* xb8 = (unsigned char*)ws;      ws += sizeof(char) * NN * HID;
    unsigned char* h8  = (unsigned char*)ws;      ws += sizeof(char) * NN * HID;

    // co-resident grid size: query once (host-side, capture-safe), cache.
    static int s_grid = 0;
    if (s_grid == 0) {
        int occ = 0;
        hipError_t err = hipOccupancyMaxActiveBlocksPerMultiprocessor(&occ, k_mega, 256, 0);
        int ncu = 256;
        hipDeviceProp_t prop;
        int dev = 0;
        if (hipGetDevice(&dev) == hipSuccess &&
            hipGetDeviceProperties(&prop, dev) == hipSuccess)
            ncu = prop.multiProcessorCount;
        long g = (err == hipSuccess && occ > 0) ? (long)occ * ncu : 1024;
        if (g > 2048) g = 2048;
        if (g < GP) g = GP;
        s_grid = (int)g;
    }

    void* kargs[] = {
        (void*)&x, (void*)&row, (void*)&col, (void*)&ew,
        (void*)&W1_0, (void*)&W1_1, (void*)&b1,
        (void*)&W2_0, (void*)&W2_1, (void*)&b2, (void*)&out,
        (void*)&partS, (void*)&partC, (void*)&bucketCursor, (void*)&rowptr,
        (void*)&dinv, (void*)&xa, (void*)&h16, (void*)&g16,
        (void*)&xb8, (void*)&h8
    };
    hipLaunchCooperativeKernel((void*)k_mega, dim3(s_grid), dim3(256),
                               kargs, 0, stream);
}

// Round 7
// 205.515 us; speedup vs baseline: 3.1253x; 3.1253x over previous
//
#include <hip/hip_runtime.h>
#include <hip/hip_bf16.h>
#include <hip/hip_fp16.h>

// DFAChebNet forward.
//  layer: x@W0 + (agg(x)-x)@W1 + b == x@(W0-W1) + agg(x@W1) + b   (project first)
//  aggregation: CSR pull-gather; CSR built by LDS counting sort.
//  R18: R17's cooperative mega-kernel regressed 3x (grid.sync across 8
//  non-coherent XCDs flushes L2 -> every phase restarts cold; same bytes,
//  same VALU work, 5x time). Revert to R16 structure; cut dispatches 7->5 by
//  block-local fusion (no global sync needed):
//   - proj1 merged into k_bucket_sort: block b computes dinv for its own 256
//     rows == 16 proj1 MFMA tiles; dinv passed via LDS.
//   - lsm merged into k_gather2: block = 16-node tile, 4 waves x 4-chain
//     interleaved gather (g kept in 512B LDS), wave 0 does lsm MFMA+softmax.
//     g16 global round-trip eliminated.
//  All math R16-verbatim (same reduction orders).

constexpr int NN   = 100000;
constexpr int NE   = 1600000;
constexpr int FIN  = 128;
constexpr int HID  = 16;
constexpr int NCLS = 32;

constexpr int RB    = 256;                         // rows per bucket
constexpr int NBKT  = (NN + RB - 1) / RB;          // 391
constexpr int EPB   = 4096;                        // edges per partition block
constexpr int EPT   = EPB / 256;                   // 16 edges per thread
constexpr int GP    = (NE + EPB - 1) / EPB;        // 391
constexpr int CAP   = 8192;                        // bucket slot capacity (mean 4096)
constexpr int NTILE = NN / 16;                     // 6250 MFMA tiles (exact)
constexpr int NPAIR = NN / 2;                      // 50000 dual-node waves

typedef float f32x2 __attribute__((ext_vector_type(2)));
typedef float f32x4 __attribute__((ext_vector_type(4)));
typedef short bf16x8 __attribute__((ext_vector_type(8)));

#if defined(__has_builtin)
#if __has_builtin(__builtin_amdgcn_cvt_pk_f32_fp8)
#define HAVE_CVT_FP8 1
#endif
#endif

// fp8 e4m3fn encode (RNE, subnormals flushed to 0, clamp at 448)
static __device__ __forceinline__ unsigned int f2e4m3(float f) {
    union { float f; unsigned int u; } v; v.f = f;
    unsigned int s = (v.u >> 24) & 0x80u;
    unsigned int au = v.u & 0x7fffffffu;
    if (au > 0x43E00000u) au = 0x43E00000u;        // clamp to 448
    au += 0x7ffffu + ((au >> 20) & 1u);            // RNE into 3-bit mantissa
    int e4 = (int)(au >> 23) - 120;                // 127-7
    unsigned int m = (au >> 20) & 7u;
    unsigned int byte = (e4 <= 0) ? 0u : (((unsigned int)e4 << 3) | m);
    return s | byte;
}
// 4 packed fp8 -> acc[0..3] += w * val
static __device__ __forceinline__ void fp8x4_fma(unsigned int v, float w, float* acc) {
#ifdef HAVE_CVT_FP8
    f32x2 lo = __builtin_amdgcn_cvt_pk_f32_fp8((int)v, false);
    f32x2 hi = __builtin_amdgcn_cvt_pk_f32_fp8((int)v, true);
    acc[0] += w * lo.x; acc[1] += w * lo.y;
    acc[2] += w * hi.x; acc[3] += w * hi.y;
#else
#pragma unroll
    for (int i = 0; i < 4; i++) {
        unsigned int b = (v >> (8 * i)) & 0xffu;
        float f = __int_as_float((int)(((b & 0x80u) << 24) | ((b & 0x7fu) << 20))) * 0x1p120f;
        acc[i] += w * f;
    }
#endif
}
// bf16 RNE
static __device__ __forceinline__ unsigned short f2bf(float f) {
    union { float f; unsigned int u; } v; v.f = f;
    unsigned int r = v.u + 0x7fffu + ((v.u >> 16) & 1u);
    return (unsigned short)(r >> 16);
}
// edge record: col(17 bits) | w(15 bits = signless bf16, RNE)
static __device__ __forceinline__ unsigned int wpack(float wf) {
    unsigned int b = __float_as_uint(wf) + 0x8000u;
    return (b >> 16) & 0x7fffu;
}
static __device__ __forceinline__ float wdec(unsigned int u) {
    return __uint_as_float((u >> 17) << 16);
}

// ---- zero the bucket cursors ----
__global__ void k_zero_cur(int* __restrict__ bucketCursor) {
    int i = blockIdx.x * blockDim.x + threadIdx.x;
    if (i < NBKT) bucketCursor[i] = 0;
}

// ---- pass B: LDS-staged partition; atomic reservation into slotted buffer ----
__global__ __launch_bounds__(256) void k_partition(
    const int* __restrict__ row, const int* __restrict__ col,
    const float* __restrict__ w, int* __restrict__ bucketCursor,
    int2* __restrict__ partS) {
    __shared__ int2 stage[EPB];              // 32KB
    __shared__ unsigned short sbkt[EPB];     // 8KB
    __shared__ int cnt[NBKT];
    __shared__ int lofs[NBKT];
    __shared__ int cursor[NBKT];
    __shared__ int gbase[NBKT];
    __shared__ int sa[512], sb[512];
    int tid = threadIdx.x;
    long ebase = (long)blockIdx.x * EPB;
    int rr[EPT]; int cc[EPT]; float wv[EPT];
#pragma unroll
    for (int i = 0; i < EPT; i++) {
        long e = ebase + i * 256 + tid;
        if (e < NE) { rr[i] = row[e]; cc[i] = col[e]; wv[i] = w[e]; }
        else rr[i] = -1;
    }
    for (int i = tid; i < NBKT; i += 256) cnt[i] = 0;
    __syncthreads();
#pragma unroll
    for (int i = 0; i < EPT; i++)
        if (rr[i] >= 0) atomicAdd(&cnt[rr[i] >> 8], 1);
    __syncthreads();
    for (int i = tid; i < 512; i += 256) sa[i] = (i < NBKT) ? cnt[i] : 0;
    __syncthreads();
    int* src = sa; int* dst = sb;
    for (int off = 1; off < 512; off <<= 1) {
        for (int i = tid; i < 512; i += 256)
            dst[i] = src[i] + ((i >= off) ? src[i - off] : 0);
        __syncthreads();
        int* t = src; src = dst; dst = t;
    }
    for (int i = tid; i < NBKT; i += 256) {
        int ex = src[i] - cnt[i];
        lofs[i] = ex;
        cursor[i] = ex;
        int go = (cnt[i] > 0) ? atomicAdd(&bucketCursor[i], cnt[i]) : 0;
        gbase[i] = i * CAP + go;
    }
    __syncthreads();
#pragma unroll
    for (int i = 0; i < EPT; i++) {
        if (rr[i] >= 0) {
            int b = rr[i] >> 8;
            int p = atomicAdd(&cursor[b], 1);
            int2 v;
            v.x = cc[i] | ((rr[i] & 255) << 17);
            v.y = __float_as_int(wv[i]);
            stage[p] = v;
            sbkt[p] = (unsigned short)b;
        }
    }
    __syncthreads();
    int total = (int)min((long)EPB, NE - ebase);
    for (int i = tid; i < total; i += 256) {
        int b = sbkt[i];
        partS[gbase[b] + (i - lofs[b])] = stage[i];
    }
}

// ---- pass C (R18: + fused proj1): per-bucket sort by row -> packed CSR,
// rowptr, dinv; THEN (block-local) proj1 for the block's own 256 rows:
//   xa = x@(W1_0-W1_1)+b1 ; xb8 = fp8(dinv * (x@W1_1))
// 16 MFMA tiles per block (4 per wave), dinv via LDS -- no global re-read.
__global__ __launch_bounds__(256) void k_bucket_sort_proj1(
    const int2* __restrict__ partS, const int* __restrict__ bucketCursor,
    unsigned int* __restrict__ partC, int* __restrict__ rowptr,
    float* __restrict__ dinv,
    const float* __restrict__ x, const float* __restrict__ W1_0,
    const float* __restrict__ W1_1, const float* __restrict__ b1,
    float* __restrict__ xa, unsigned char* __restrict__ xb8) {
    __shared__ int hist[RB];
    __shared__ int cursor[RB];
    __shared__ float dsum[RB];
    __shared__ float sh_dinv[RB];
    __shared__ int wtot[4];
    __shared__ int red[4];
    int b = blockIdx.x;
    int tid = threadIdx.x;
    int lane = tid & 63, wv = tid >> 6;
    // inline exclusive scan: start = sum_{i<b} count_i
    int partial = 0;
    for (int i = tid; i < b; i += 256) partial += bucketCursor[i];
#pragma unroll
    for (int off = 1; off < 64; off <<= 1) partial += __shfl_xor(partial, off, 64);
    if (lane == 0) red[wv] = partial;
    hist[tid] = 0;
    dsum[tid] = 0.f;
    __syncthreads();
    int start = red[0] + red[1] + red[2] + red[3];
    int count = bucketCursor[b];
    const int2* src = partS + (long)b * CAP;
    for (int i = tid; i < count; i += 256)
        atomicAdd(&hist[((unsigned)src[i].x >> 17) & 255], 1);
    __syncthreads();
    int v = hist[tid];
    int sc = v;
#pragma unroll
    for (int off = 1; off < 64; off <<= 1) {
        int up = __shfl_up(sc, off, 64);
        if (lane >= off) sc += up;
    }
    if (lane == 63) wtot[wv] = sc;
    __syncthreads();
    int add = 0;
    for (int w2 = 0; w2 < wv; w2++) add += wtot[w2];
    int ex = sc + add - v;
    int node = b * RB + tid;
    if (node <= NN) rowptr[node] = start + ex;   // node==NN -> NE (last bucket)
    cursor[tid] = ex;
    __syncthreads();
    for (int i = tid; i < count; i += 256) {
        int2 p = src[i];
        int rl = ((unsigned)p.x >> 17) & 255;
        int pos = atomicAdd(&cursor[rl], 1);
        float wf = __int_as_float(p.y);
        partC[start + pos] = ((unsigned)p.x & 0x1FFFFu) | (wpack(wf) << 17);
        atomicAdd(&dsum[rl], wf);
    }
    __syncthreads();
    {
        float dsv = dsum[tid];
        float dv = dsv > 0.f ? rsqrtf(dsv) : 0.f;
        if (node < NN) dinv[node] = dv;
        sh_dinv[tid] = dv;
    }
    __syncthreads();

    // ---- fused proj1 over this block's 16 tiles (4 per wave) ----
    {
        int pcol = lane & 15, quad = lane >> 4;
        bf16x8 bfrag[2][4];
#pragma unroll
        for (int mat = 0; mat < 2; mat++) {
            const float* W = mat ? W1_1 : W1_0;
#pragma unroll
            for (int kb = 0; kb < 4; kb++) {
                bf16x8 f;
#pragma unroll
                for (int j = 0; j < 8; j++)
                    f[j] = (short)f2bf(W[(kb * 32 + quad * 8 + j) * HID + pcol]);
                bfrag[mat][kb] = f;
            }
        }
        float b1v = b1[pcol];
#pragma unroll
        for (int i = 0; i < 4; i++) {
            int tb = wv * 4 + i;
            int wid = b * 16 + tb;
            if (wid >= NTILE) break;
            const float* xrow = x + ((long)wid * 16 + pcol) * FIN + quad * 8;
            float4 xb[8];
#pragma unroll
            for (int kb = 0; kb < 4; kb++) {
                xb[2 * kb]     = *(const float4*)(xrow + kb * 32);
                xb[2 * kb + 1] = *(const float4*)(xrow + kb * 32 + 4);
            }
            f32x4 acc0 = {0.f, 0.f, 0.f, 0.f}, acc1 = {0.f, 0.f, 0.f, 0.f};
#pragma unroll
            for (int kb = 0; kb < 4; kb++) {
                float4 a0 = xb[2 * kb], a1 = xb[2 * kb + 1];
                bf16x8 af;
                af[0] = (short)f2bf(a0.x); af[1] = (short)f2bf(a0.y);
                af[2] = (short)f2bf(a0.z); af[3] = (short)f2bf(a0.w);
                af[4] = (short)f2bf(a1.x); af[5] = (short)f2bf(a1.y);
                af[6] = (short)f2bf(a1.z); af[7] = (short)f2bf(a1.w);
                acc0 = __builtin_amdgcn_mfma_f32_16x16x32_bf16(af, bfrag[0][kb], acc0, 0, 0, 0);
                acc1 = __builtin_amdgcn_mfma_f32_16x16x32_bf16(af, bfrag[1][kb], acc1, 0, 0, 0);
            }
#pragma unroll
            for (int r = 0; r < 4; r++) {
                int lidx = tb * 16 + quad * 4 + r;          // in-block row
                long nd = (long)b * RB + lidx;
                float a0 = acc0[r], a1 = acc1[r];
                xa[nd * HID + pcol] = a0 - a1 + b1v;
                float dn = sh_dinv[lidx];
                xb8[nd * HID + pcol] = (unsigned char)f2e4m3(dn * a1);
            }
        }
    }
}

// Layer-1 gather, lean (R16-verbatim). 1 wave = adjacent node pair, chains
// interleaved. h16 = bf16(relu(xa + dn*agg(xb8))), h8 = fp8(dn*h).
// lane = (d = dword 0..3, p = edge parity 0..15).
__global__ __launch_bounds__(256) void k_gather1(
    const int* __restrict__ rowptr, const unsigned int* __restrict__ partC,
    const float* __restrict__ dinv, const unsigned char* __restrict__ xb8,
    const float* __restrict__ xa,
    unsigned short* __restrict__ h16, unsigned char* __restrict__ h8) {
    long t = (long)blockIdx.x * 256 + threadIdx.x;
    int w = (int)(t >> 6);
    if (w >= NPAIR) return;
    int lane = threadIdx.x & 63;
    int d = lane & 3, p = lane >> 2;
    long n0 = (long)w * 2, n1 = n0 + 1;

    int s0 = rowptr[n0], e0 = rowptr[n0 + 1], e1 = rowptr[n0 + 2];
    float2 dnv = *(const float2*)(dinv + n0);
    float4 xav0 = *(const float4*)(xa + n0 * HID + d * 4);
    float4 xav1 = *(const float4*)(xa + n1 * HID + d * 4);

    float acc0[4] = {0.f, 0.f, 0.f, 0.f};
    float acc1[4] = {0.f, 0.f, 0.f, 0.f};
    int j0 = s0 + p, j1 = e0 + p;      // n1's range starts at e0
    while ((j0 < e0) | (j1 < e1)) {
        if (j0 < e0) {
            unsigned int u = partC[j0];
            unsigned int v = *(const unsigned int*)(xb8 + (u & 0x1FFFF) * HID + d * 4);
            fp8x4_fma(v, wdec(u), acc0);
            j0 += 16;
        }
        if (j1 < e1) {
            unsigned int u = partC[j1];
            unsigned int v = *(const unsigned int*)(xb8 + (u & 0x1FFFF) * HID + d * 4);
            fp8x4_fma(v, wdec(u), acc1);
            j1 += 16;
        }
    }
#pragma unroll
    for (int i = 0; i < 4; i++) {
        acc0[i] += __shfl_xor(acc0[i], 4);  acc1[i] += __shfl_xor(acc1[i], 4);
        acc0[i] += __shfl_xor(acc0[i], 8);  acc1[i] += __shfl_xor(acc1[i], 8);
        acc0[i] += __shfl_xor(acc0[i], 16); acc1[i] += __shfl_xor(acc1[i], 16);
        acc0[i] += __shfl_xor(acc0[i], 32); acc1[i] += __shfl_xor(acc1[i], 32);
    }
    if (p == 0) {   // lanes 0..3 (lane == d)
        float h0[4], h1[4];
        h0[0] = fmaxf(xav0.x + dnv.x * acc0[0], 0.f);
        h0[1] = fmaxf(xav0.y + dnv.x * acc0[1], 0.f);
        h0[2] = fmaxf(xav0.z + dnv.x * acc0[2], 0.f);
        h0[3] = fmaxf(xav0.w + dnv.x * acc0[3], 0.f);
        h1[0] = fmaxf(xav1.x + dnv.y * acc1[0], 0.f);
        h1[1] = fmaxf(xav1.y + dnv.y * acc1[1], 0.f);
        h1[2] = fmaxf(xav1.z + dnv.y * acc1[2], 0.f);
        h1[3] = fmaxf(xav1.w + dnv.y * acc1[3], 0.f);
        ushort4 u0, u1;
        u0.x = f2bf(h0[0]); u0.y = f2bf(h0[1]); u0.z = f2bf(h0[2]); u0.w = f2bf(h0[3]);
        u1.x = f2bf(h1[0]); u1.y = f2bf(h1[1]); u1.z = f2bf(h1[2]); u1.w = f2bf(h1[3]);
        *(ushort4*)(h16 + n0 * HID + d * 4) = u0;
        *(ushort4*)(h16 + n1 * HID + d * 4) = u1;
        unsigned int p0 = f2e4m3(dnv.x * h0[0]) | (f2e4m3(dnv.x * h0[1]) << 8)
                        | (f2e4m3(dnv.x * h0[2]) << 16) | (f2e4m3(dnv.x * h0[3]) << 24);
        unsigned int p1 = f2e4m3(dnv.y * h1[0]) | (f2e4m3(dnv.y * h1[1]) << 8)
                        | (f2e4m3(dnv.y * h1[2]) << 16) | (f2e4m3(dnv.y * h1[3]) << 24);
        *(unsigned int*)(h8 + n0 * HID + d * 4) = p0;
        *(unsigned int*)(h8 + n1 * HID + d * 4) = p1;
    }
}

// Layer-2 gather + final projection + log-softmax (R18).
//  1 block = one 16-node tile. 4 waves x 4-chain interleaved gather:
//  wave wv owns nodes tile*16 + wv*4 + {0..3}; g = bf16(dn*agg(h8)) goes to
//  512B LDS. Then wave 0: v = [h16;g]@[W2_0-W2_1;W2_1] + b2 (two 16x16x32
//  bf16 MFMAs, K=32 concat) and log-softmax (R16-verbatim math).
__global__ __launch_bounds__(256) void k_gather2_lsm(
    const int* __restrict__ rowptr, const unsigned int* __restrict__ partC,
    const float* __restrict__ dinv, const unsigned char* __restrict__ h8,
    const unsigned short* __restrict__ h16,
    const float* __restrict__ W2_0, const float* __restrict__ W2_1,
    const float* __restrict__ b2, float* __restrict__ out) {
    __shared__ unsigned short sh_g[16][16];     // bf16 g for the tile
    int tile = blockIdx.x;
    int tid = threadIdx.x;
    int lane = tid & 63, wv = tid >> 6;
    int d = lane & 3, p = lane >> 2;
    int nb = tile * 16 + wv * 4;                 // wave's first node

    int s[5];
#pragma unroll
    for (int k = 0; k < 5; k++) s[k] = rowptr[nb + k];
    float4 dn4 = *(const float4*)(dinv + nb);

    float acc[4][4];
#pragma unroll
    for (int c = 0; c < 4; c++)
#pragma unroll
        for (int i = 0; i < 4; i++) acc[c][i] = 0.f;

    int j0 = s[0] + p, j1 = s[1] + p, j2 = s[2] + p, j3 = s[3] + p;
    int e0 = s[1], e1 = s[2], e2 = s[3], e3 = s[4];
    while ((j0 < e0) | (j1 < e1) | (j2 < e2) | (j3 < e3)) {
        if (j0 < e0) {
            unsigned int u = partC[j0];
            unsigned int v = *(const unsigned int*)(h8 + (u & 0x1FFFF) * HID + d * 4);
            fp8x4_fma(v, wdec(u), acc[0]);
            j0 += 16;
        }
        if (j1 < e1) {
            unsigned int u = partC[j1];
            unsigned int v = *(const unsigned int*)(h8 + (u & 0x1FFFF) * HID + d * 4);
            fp8x4_fma(v, wdec(u), acc[1]);
            j1 += 16;
        }
        if (j2 < e2) {
            unsigned int u = partC[j2];
            unsigned int v = *(const unsigned int*)(h8 + (u & 0x1FFFF) * HID + d * 4);
            fp8x4_fma(v, wdec(u), acc[2]);
            j2 += 16;
        }
        if (j3 < e3) {
            unsigned int u = partC[j3];
            unsigned int v = *(const unsigned int*)(h8 + (u & 0x1FFFF) * HID + d * 4);
            fp8x4_fma(v, wdec(u), acc[3]);
            j3 += 16;
        }
    }
#pragma unroll
    for (int i = 0; i < 4; i++) {
        acc[0][i] += __shfl_xor(acc[0][i], 4);  acc[1][i] += __shfl_xor(acc[1][i], 4);
        acc[2][i] += __shfl_xor(acc[2][i], 4);  acc[3][i] += __shfl_xor(acc[3][i], 4);
        acc[0][i] += __shfl_xor(acc[0][i], 8);  acc[1][i] += __shfl_xor(acc[1][i], 8);
        acc[2][i] += __shfl_xor(acc[2][i], 8);  acc[3][i] += __shfl_xor(acc[3][i], 8);
        acc[0][i] += __shfl_xor(acc[0][i], 16); acc[1][i] += __shfl_xor(acc[1][i], 16);
        acc[2][i] += __shfl_xor(acc[2][i], 16); acc[3][i] += __shfl_xor(acc[3][i], 16);
        acc[0][i] += __shfl_xor(acc[0][i], 32); acc[1][i] += __shfl_xor(acc[1][i], 32);
        acc[2][i] += __shfl_xor(acc[2][i], 32); acc[3][i] += __shfl_xor(acc[3][i], 32);
    }
    if (p == 0) {   // lanes 0..3 (lane == d)
        float dnc[4] = {dn4.x, dn4.y, dn4.z, dn4.w};
#pragma unroll
        for (int c = 0; c < 4; c++) {
            ushort4 u;
            u.x = f2bf(dnc[c] * acc[c][0]); u.y = f2bf(dnc[c] * acc[c][1]);
            u.z = f2bf(dnc[c] * acc[c][2]); u.w = f2bf(dnc[c] * acc[c][3]);
            *(ushort4*)&sh_g[wv * 4 + c][d * 4] = u;
        }
    }
    __syncthreads();

    if (wv == 0) {
        int pcol = lane & 15, quad = lane >> 4;
        // B frags: Bcomb[k][o] = k<16 ? W2_0[k][o]-W2_1[k][o] : W2_1[k-16][o]
        bf16x8 bfrag[2];
#pragma unroll
        for (int c = 0; c < 2; c++) {
            bf16x8 f;
            if (quad < 2) {
#pragma unroll
                for (int j = 0; j < 8; j++) {
                    int k = quad * 8 + j;
                    f[j] = (short)f2bf(W2_0[k * NCLS + pcol + 16 * c] - W2_1[k * NCLS + pcol + 16 * c]);
                }
            } else {
#pragma unroll
                for (int j = 0; j < 8; j++) {
                    int k = (quad - 2) * 8 + j;
                    f[j] = (short)f2bf(W2_1[k * NCLS + pcol + 16 * c]);
                }
            }
            bfrag[c] = f;
        }
        // A frag: quads 0,1 from global h16; quads 2,3 from LDS g
        bf16x8 af;
        if (quad < 2)
            af = *(const bf16x8*)(h16 + ((long)tile * 16 + pcol) * HID + (quad & 1) * 8);
        else
            af = *(const bf16x8*)&sh_g[pcol][(quad & 1) * 8];

        f32x4 c0 = {0.f, 0.f, 0.f, 0.f}, c1 = {0.f, 0.f, 0.f, 0.f};
        c0 = __builtin_amdgcn_mfma_f32_16x16x32_bf16(af, bfrag[0], c0, 0, 0, 0);
        c1 = __builtin_amdgcn_mfma_f32_16x16x32_bf16(af, bfrag[1], c1, 0, 0, 0);

        float b2a = b2[pcol], b2b = b2[pcol + 16];
#pragma unroll
        for (int r = 0; r < 4; r++) {
            long node = (long)tile * 16 + quad * 4 + r;
            float v0 = c0[r] + b2a;
            float v1 = c1[r] + b2b;
            float m = fmaxf(v0, v1);
            m = fmaxf(m, __shfl_xor(m, 1));
            m = fmaxf(m, __shfl_xor(m, 2));
            m = fmaxf(m, __shfl_xor(m, 4));
            m = fmaxf(m, __shfl_xor(m, 8));
            float sum = __expf(v0 - m) + __expf(v1 - m);
            sum += __shfl_xor(sum, 1);
            sum += __shfl_xor(sum, 2);
            sum += __shfl_xor(sum, 4);
            sum += __shfl_xor(sum, 8);
            float ls = logf(sum);
            out[node * NCLS + pcol] = v0 - m - ls;
            out[node * NCLS + pcol + 16] = v1 - m - ls;
        }
    }
}

extern "C" void kernel_launch(void* const* d_in, const int* in_sizes, int n_in,
                              void* d_out, int out_size, void* d_ws, size_t ws_size,
                              hipStream_t stream) {
    const float* x    = (const float*)d_in[0];
    const int*   ei   = (const int*)d_in[1];
    const float* ew   = (const float*)d_in[2];
    const float* W1_0 = (const float*)d_in[3];
    const float* W1_1 = (const float*)d_in[4];
    const float* b1   = (const float*)d_in[5];
    const float* W2_0 = (const float*)d_in[6];
    const float* W2_1 = (const float*)d_in[7];
    const float* b2   = (const float*)d_in[8];
    float* out = (float*)d_out;

    const int* row = ei;
    const int* col = ei + NE;

    char* ws = (char*)d_ws;
    int2*  partS     = (int2*)ws;                 ws += sizeof(int2) * (long)NBKT * CAP;
    unsigned int* partC = (unsigned int*)ws;      ws += sizeof(int) * NE;
    int*   bucketCursor = (int*)ws;               ws += sizeof(int) * NBKT;
    int*   rowptr    = (int*)ws;                  ws += sizeof(int) * (NN + 4);
    float* dinv      = (float*)ws;                ws += sizeof(float) * NN;
    float* xa        = (float*)ws;                ws += sizeof(float) * NN * HID;
    unsigned short* h16 = (unsigned short*)ws;    ws += sizeof(short) * NN * HID;
    unsigned char* xb8 = (unsigned char*)ws;      ws += sizeof(char) * NN * HID;
    unsigned char* h8  = (unsigned char*)ws;      ws += sizeof(char) * NN * HID;

    k_zero_cur<<<(NBKT + 255) / 256, 256, 0, stream>>>(bucketCursor);
    k_partition<<<GP, 256, 0, stream>>>(row, col, ew, bucketCursor, partS);
    k_bucket_sort_proj1<<<NBKT, 256, 0, stream>>>(partS, bucketCursor, partC,
                                                  rowptr, dinv, x, W1_0, W1_1,
                                                  b1, xa, xb8);
    {
        long th = (long)NPAIR * 64;
        k_gather1<<<(int)((th + 255) / 256), 256, 0, stream>>>(
            rowptr, partC, dinv, xb8, xa, h16, h8);
    }
    k_gather2_lsm<<<NTILE, 256, 0, stream>>>(rowptr, partC, dinv, h8, h16,
                                             W2_0, W2_1, b2, out);
}